// Round 2
// baseline (619.677 us; speedup 1.0000x reference)
//
#include <hip/hip_runtime.h>
#include <hip/hip_bf16.h>

typedef unsigned short u16;
typedef unsigned int u32;
typedef __attribute__((ext_vector_type(8))) short bf16x8;
typedef __attribute__((ext_vector_type(4))) float f32x4;
typedef __attribute__((ext_vector_type(8))) u16 u16x8;
typedef __attribute__((ext_vector_type(4))) u16 u16x4;

#define NN 20000
#define NE 320000
#define HC 512     // heads*channels = 4*128

__device__ __forceinline__ float bf2f(u16 u){ return __uint_as_float(((u32)u)<<16); }
__device__ __forceinline__ u16 f2bf(float x){
  __hip_bfloat16 h = __float2bfloat16(x);
  return *reinterpret_cast<u16*>(&h);
}

// ---------------- cast x f32 -> bf16 ----------------
__global__ __launch_bounds__(256) void cast_kernel(const float* __restrict__ in, u16* __restrict__ out, int total){
  int i = (blockIdx.x*256 + threadIdx.x)*4;
  if (i >= total) return;
  float4 v = *(const float4*)(in + i);
  u16x4 o = { f2bf(v.x), f2bf(v.y), f2bf(v.z), f2bf(v.w) };
  *(u16x4*)(out + i) = o;
}

// ---------------- transpose+cast W f32 [K,N] -> WT bf16 [N,K] ----------------
__global__ __launch_bounds__(256) void transpose_cast(const float* __restrict__ W, u16* __restrict__ WT,
                                                      int K, int N){
  __shared__ u16 t[32][33];
  int bx = blockIdx.x*32;   // along N
  int by = blockIdx.y*32;   // along K
  int tx = threadIdx.x & 31, ty = threadIdx.x >> 5;  // 32x8
  for (int r = ty; r < 32; r += 8) t[r][tx] = f2bf(W[(size_t)(by+r)*N + bx + tx]);
  __syncthreads();
  for (int r = ty; r < 32; r += 8) WT[(size_t)(bx+r)*K + by + tx] = t[tx][r];
}

// ---------------- edge dtype detect + normalize ----------------
__global__ void detect_kernel(const int* __restrict__ ei, int* __restrict__ flag){
  __shared__ int nz;
  if (threadIdx.x == 0) nz = 0;
  __syncthreads();
  int c = 0;
  for (int k = threadIdx.x; k < 4096; k += 256) if (ei[2*k + 1] != 0) c++;
  atomicAdd(&nz, c);
  __syncthreads();
  if (threadIdx.x == 0) *flag = (nz == 0) ? 1 : 0;   // 1 => data is int64
}

__global__ __launch_bounds__(256) void normalize_edges(const int* __restrict__ ei, const int* __restrict__ flag,
    int* __restrict__ src, int* __restrict__ dst, int E){
  int e = blockIdx.x*256 + threadIdx.x;
  if (e >= E) return;
  if (*flag){ src[e] = ei[2*e]; dst[e] = ei[2*(E + e)]; }
  else      { src[e] = ei[e];   dst[e] = ei[E + e]; }
}

// ---------------- GEMM: C[M,512](bf16) = A[M,K](bf16) * BT[512,K](bf16)^T ----------------
__global__ __launch_bounds__(256) void gemm_bf16(const u16* __restrict__ A, const u16* __restrict__ BT,
                                                 u16* __restrict__ C, int M, int K){
  __shared__ __align__(16) u16 Ads[128][64];
  __shared__ __align__(16) u16 Bds[128][64];
  const int bm = blockIdx.x, bn = blockIdx.y;
  const int tid = threadIdx.x;
  const int lane = tid & 63, wid = tid >> 6;
  const int wr = (wid >> 1) << 6, wc = (wid & 1) << 6;
  f32x4 acc[4][4] = {};
  const int row0 = bm*128;
  for (int k0 = 0; k0 < K; k0 += 64){
    #pragma unroll
    for (int p = 0; p < 4; ++p){
      int idx = p*256 + tid;
      int r = idx >> 3;
      int c = (idx & 7) << 3;
      int cs = c ^ ((r & 7) << 3);   // XOR swizzle (16B granules)
      u16x8 va = {};
      int gr = row0 + r;
      if (gr < M) va = *(const u16x8*)(A + (size_t)gr*K + k0 + c);
      *(u16x8*)&Ads[r][cs] = va;
      u16x8 vb = *(const u16x8*)(BT + (size_t)(bn*128 + r)*K + k0 + c);
      *(u16x8*)&Bds[r][cs] = vb;
    }
    __syncthreads();
    #pragma unroll
    for (int kk = 0; kk < 64; kk += 32){
      const int lr = lane & 15;
      const int lk = kk + ((lane >> 4) << 3);
      bf16x8 a[4], b[4];
      #pragma unroll
      for (int i = 0; i < 4; ++i){
        int ar = wr + 16*i + lr;
        a[i] = *(const bf16x8*)&Ads[ar][lk ^ ((ar & 7) << 3)];
      }
      #pragma unroll
      for (int j = 0; j < 4; ++j){
        int br = wc + 16*j + lr;
        b[j] = *(const bf16x8*)&Bds[br][lk ^ ((br & 7) << 3)];
      }
      #pragma unroll
      for (int i = 0; i < 4; ++i)
        #pragma unroll
        for (int j = 0; j < 4; ++j)
          acc[i][j] = __builtin_amdgcn_mfma_f32_16x16x32_bf16(a[i], b[j], acc[i][j], 0, 0, 0);
    }
    __syncthreads();
  }
  const int lr = lane & 15, r4 = (lane >> 4) << 2;
  #pragma unroll
  for (int i = 0; i < 4; ++i)
    #pragma unroll
    for (int j = 0; j < 4; ++j){
      int col = bn*128 + wc + 16*j + lr;
      #pragma unroll
      for (int r = 0; r < 4; ++r){
        int row = row0 + wr + 16*i + r4 + r;
        if (row < M) C[(size_t)row*HC + col] = f2bf(acc[i][j][r]);
      }
    }
}

// ---------------- per-node attention coefficients a_s, a_d ----------------
__global__ __launch_bounds__(256) void asad_kernel(const u16* __restrict__ h,
    const float* __restrict__ attS, const float* __restrict__ attD,
    float* __restrict__ a_s, float* __restrict__ a_d, int N){
  int wid = blockIdx.x*4 + (threadIdx.x >> 6);
  if (wid >= N) return;
  int lane = threadIdx.x & 63;
  u16x8 v = *(const u16x8*)(h + (size_t)wid*HC + lane*8);
  float4 s0 = *(const float4*)(attS + lane*8);
  float4 s1 = *(const float4*)(attS + lane*8 + 4);
  float4 d0 = *(const float4*)(attD + lane*8);
  float4 d1 = *(const float4*)(attD + lane*8 + 4);
  float sv[8] = {s0.x,s0.y,s0.z,s0.w,s1.x,s1.y,s1.z,s1.w};
  float dv[8] = {d0.x,d0.y,d0.z,d0.w,d1.x,d1.y,d1.z,d1.w};
  float ps = 0.f, pd = 0.f;
  #pragma unroll
  for (int t = 0; t < 8; ++t){ float hv = bf2f(v[t]); ps += hv*sv[t]; pd += hv*dv[t]; }
  #pragma unroll
  for (int off = 1; off < 16; off <<= 1){
    ps += __shfl_xor(ps, off, 64);
    pd += __shfl_xor(pd, off, 64);
  }
  if ((lane & 15) == 0){
    int hh = lane >> 4;
    a_s[wid*4 + hh] = ps;
    a_d[wid*4 + hh] = pd;
  }
}

// ---------------- edge sort by dst: histogram / scan / scatter ----------------
__global__ __launch_bounds__(256) void hist_kernel(const int* __restrict__ dst, int* __restrict__ cnt, int E){
  int e = blockIdx.x*256 + threadIdx.x;
  if (e < E) atomicAdd(&cnt[dst[e]], 1);
}

__global__ __launch_bounds__(1024) void scan_kernel(const int* __restrict__ cnt,
    int* __restrict__ offs, int* __restrict__ cur, int N){
  __shared__ int buf[1024];
  __shared__ int carry_s;
  int tid = threadIdx.x;
  if (tid == 0) carry_s = 0;
  __syncthreads();
  for (int base = 0; base < N; base += 1024){
    int i = base + tid;
    int v = (i < N) ? cnt[i] : 0;
    buf[tid] = v;
    __syncthreads();
    for (int off = 1; off < 1024; off <<= 1){
      int t = (tid >= off) ? buf[tid - off] : 0;
      __syncthreads();
      buf[tid] += t;
      __syncthreads();
    }
    int carry = carry_s;
    int excl = carry + buf[tid] - v;
    if (i < N){ offs[i] = excl; cur[i] = excl; }
    __syncthreads();
    if (tid == 1023) carry_s = carry + buf[1023];
    __syncthreads();
  }
  if (tid == 0) offs[N] = carry_s;
}

__global__ __launch_bounds__(256) void scatter_kernel(const int* __restrict__ src, const int* __restrict__ dst,
    int* __restrict__ cur, int* __restrict__ src_sorted, int* __restrict__ sortpos, int E){
  int e = blockIdx.x*256 + threadIdx.x;
  if (e >= E) return;
  int d = dst[e];
  int pos = atomicAdd(&cur[d], 1);
  src_sorted[pos] = src[e];
  sortpos[e] = pos;
}

// ---------------- edge pass: score = exp(leaky(a_s+a_d)) + segment sum ----------------
__global__ __launch_bounds__(256) void edge_pass(const int* __restrict__ src, const int* __restrict__ dst,
    const int* __restrict__ sortpos, const float* __restrict__ a_s, const float* __restrict__ a_d,
    float* __restrict__ score, float* __restrict__ denom, int E, int N){
  int idx = blockIdx.x*256 + threadIdx.x;
  int total = E + N;
  if (idx >= total) return;
  int s, d, spos;
  if (idx < E){ s = src[idx]; d = dst[idx]; spos = sortpos[idx]; }
  else { s = idx - E; d = s; spos = idx; }
  float4 as = *(const float4*)(a_s + s*4);
  float4 ad = *(const float4*)(a_d + d*4);
  float av[4] = {as.x+ad.x, as.y+ad.y, as.z+ad.z, as.w+ad.w};
  #pragma unroll
  for (int h = 0; h < 4; ++h){
    float x = av[h];
    float e = x > 0.f ? x : 0.2f*x;
    e = fminf(e, 80.f);            // overflow guard; ratios unchanged (max |e| ~ 25)
    float ev = expf(e);
    score[(size_t)spos*4 + h] = ev;
    atomicAdd(&denom[d*4 + h], ev);
  }
}

// ---------------- aggregation: one wave per dst node (all 512 channels) ----------------
// MODE 0/1: epilogue = +bias, leaky(0.01), -> bf16 act.  MODE 2: head-mean + b3 -> f32 hfin.
template<int MODE>
__global__ __launch_bounds__(256) void agg_kernel(const u16* __restrict__ h,
    const float* __restrict__ score, const int* __restrict__ src_sorted, const int* __restrict__ offs,
    const float* __restrict__ denom, const float* __restrict__ bias,
    void* __restrict__ outp, int N, int E){
  int d = blockIdx.x*4 + (threadIdx.x >> 6);
  if (d >= N) return;
  int lane = threadIdx.x & 63;
  int head = lane >> 4;
  float acc[8] = {};
  {
    float w = score[(size_t)(E + d)*4 + head];
    u16x8 v = *(const u16x8*)(h + (size_t)d*HC + lane*8);
    #pragma unroll
    for (int t = 0; t < 8; ++t) acc[t] += w*bf2f(v[t]);
  }
  int p0 = offs[d], p1 = offs[d+1];
  for (int p = p0; p < p1; ++p){
    int s = src_sorted[p];
    float w = score[(size_t)p*4 + head];
    u16x8 v = *(const u16x8*)(h + (size_t)s*HC + lane*8);
    #pragma unroll
    for (int t = 0; t < 8; ++t) acc[t] += w*bf2f(v[t]);
  }
  float inv = 1.0f / (denom[d*4 + head] + 1e-16f);
  if (MODE < 2){
    u16* act = (u16*)outp;
    u16x8 o;
    #pragma unroll
    for (int t = 0; t < 8; ++t){
      float x = acc[t]*inv + bias[lane*8 + t];
      x = x > 0.f ? x : 0.01f*x;
      o[t] = f2bf(x);
    }
    *(u16x8*)(act + (size_t)d*HC + lane*8) = o;
  } else {
    #pragma unroll
    for (int t = 0; t < 8; ++t){
      acc[t] *= inv;
      acc[t] += __shfl_xor(acc[t], 16, 64);
      acc[t] += __shfl_xor(acc[t], 32, 64);
    }
    if (lane < 16){
      float* hf = (float*)outp;
      int c0 = lane*8;
      float4 o0 = {0.25f*acc[0] + bias[c0+0], 0.25f*acc[1] + bias[c0+1],
                   0.25f*acc[2] + bias[c0+2], 0.25f*acc[3] + bias[c0+3]};
      float4 o1 = {0.25f*acc[4] + bias[c0+4], 0.25f*acc[5] + bias[c0+5],
                   0.25f*acc[6] + bias[c0+6], 0.25f*acc[7] + bias[c0+7]};
      *(float4*)(hf + (size_t)d*128 + c0)     = o0;
      *(float4*)(hf + (size_t)d*128 + c0 + 4) = o1;
    }
  }
}

// ---------------- final FC + split + exp -> f32 out ----------------
__global__ __launch_bounds__(128) void fc_kernel(const float* __restrict__ hfin, const float* __restrict__ W,
    const float* __restrict__ b, float* __restrict__ outp, int N){
  __shared__ float hl[128];
  int n = blockIdx.x, o = threadIdx.x;
  hl[o] = hfin[(size_t)n*128 + o];
  __syncthreads();
  float acc = b[o];
  #pragma unroll 8
  for (int k = 0; k < 128; ++k) acc += hl[k]*W[k*128 + o];
  if (o < 64) outp[(size_t)n*64 + o] = acc;
  else        outp[(size_t)N*64 + (size_t)n*64 + (o - 64)] = expf(acc);
}

extern "C" void kernel_launch(void* const* d_in, const int* in_sizes, int n_in,
                              void* d_out, int out_size, void* d_ws, size_t ws_size,
                              hipStream_t stream){
  const float* x    = (const float*)d_in[0];
  const int* ei     = (const int*)d_in[1];
  const float* W1   = (const float*)d_in[2];
  const float* att1s= (const float*)d_in[3];
  const float* att1d= (const float*)d_in[4];
  const float* b1   = (const float*)d_in[5];
  const float* W2   = (const float*)d_in[6];
  const float* att2s= (const float*)d_in[7];
  const float* att2d= (const float*)d_in[8];
  const float* b2   = (const float*)d_in[9];
  const float* W3   = (const float*)d_in[10];
  const float* att3s= (const float*)d_in[11];
  const float* att3d= (const float*)d_in[12];
  const float* b3   = (const float*)d_in[13];
  const float* fcW  = (const float*)d_in[14];
  const float* fcb  = (const float*)d_in[15];
  float* outp = (float*)d_out;

  char* ws = (char*)d_ws;
  size_t off = 0;
  auto alloc = [&](size_t bytes) -> void* {
    void* p = ws + off;
    off = (off + bytes + 255) & ~(size_t)255;
    return p;
  };
  u16*   xb     = (u16*)  alloc((size_t)NN*256*2);     // 10.2 MB
  u16*   h      = (u16*)  alloc((size_t)NN*HC*2);      // 20.5 MB
  u16*   act    = (u16*)  alloc((size_t)NN*HC*2);      // 20.5 MB
  float* hfin   = (float*)alloc((size_t)NN*128*4);     // 10.2 MB
  float* a_s    = (float*)alloc((size_t)NN*4*4);
  float* a_d    = (float*)alloc((size_t)NN*4*4);
  float* denom  = (float*)alloc((size_t)NN*4*4);
  float* score  = (float*)alloc((size_t)(NE+NN)*4*4);  // 5.4 MB
  int*   cnt    = (int*)  alloc((size_t)NN*4);
  int*   cur    = (int*)  alloc((size_t)NN*4);
  int*   offs   = (int*)  alloc((size_t)(NN+1)*4);
  int*   src32  = (int*)  alloc((size_t)NE*4);
  int*   dst32  = (int*)  alloc((size_t)NE*4);
  int*   srcs   = (int*)  alloc((size_t)NE*4);
  int*   spos   = (int*)  alloc((size_t)NE*4);
  u16*   WT1    = (u16*)  alloc((size_t)512*256*2);
  u16*   WT2    = (u16*)  alloc((size_t)512*512*2);
  u16*   WT3    = (u16*)  alloc((size_t)512*512*2);
  int*   flag   = (int*)  alloc(256);

  // ---- input prep ----
  cast_kernel<<<5000, 256, 0, stream>>>(x, xb, NN*256);
  transpose_cast<<<dim3(16, 8),  256, 0, stream>>>(W1, WT1, 256, 512);
  transpose_cast<<<dim3(16, 16), 256, 0, stream>>>(W2, WT2, 512, 512);
  transpose_cast<<<dim3(16, 16), 256, 0, stream>>>(W3, WT3, 512, 512);

  detect_kernel<<<1, 256, 0, stream>>>(ei, flag);
  normalize_edges<<<1250, 256, 0, stream>>>(ei, flag, src32, dst32, NE);

  // ---- edge sort by dst (shared across all 3 layers) ----
  hipMemsetAsync(cnt, 0, (size_t)NN*4, stream);
  hist_kernel<<<1250, 256, 0, stream>>>(dst32, cnt, NE);
  scan_kernel<<<1, 1024, 0, stream>>>(cnt, offs, cur, NN);
  scatter_kernel<<<1250, 256, 0, stream>>>(src32, dst32, cur, srcs, spos, NE);

  const int eb = (NE + NN + 255)/256;
  const float* attS[3] = {att1s, att2s, att3s};
  const float* attD[3] = {att1d, att2d, att3d};
  const u16*   WT[3]   = {WT1, WT2, WT3};
  const int    Kd[3]   = {256, 512, 512};

  for (int layer = 0; layer < 3; ++layer){
    const u16* Ain = (layer == 0) ? xb : act;
    gemm_bf16<<<dim3(157, 4), 256, 0, stream>>>(Ain, WT[layer], h, NN, Kd[layer]);
    asad_kernel<<<5000, 256, 0, stream>>>(h, attS[layer], attD[layer], a_s, a_d, NN);
    hipMemsetAsync(denom, 0, (size_t)NN*4*4, stream);
    edge_pass<<<eb, 256, 0, stream>>>(src32, dst32, spos, a_s, a_d, score, denom, NE, NN);
    if (layer == 0)
      agg_kernel<0><<<5000, 256, 0, stream>>>(h, score, srcs, offs, denom, b1, act, NN, NE);
    else if (layer == 1)
      agg_kernel<1><<<5000, 256, 0, stream>>>(h, score, srcs, offs, denom, b2, act, NN, NE);
    else
      agg_kernel<2><<<5000, 256, 0, stream>>>(h, score, srcs, offs, denom, b3, hfin, NN, NE);
  }

  fc_kernel<<<NN, 128, 0, stream>>>(hfin, fcW, fcb, outp, NN);
}

// Round 3
// 351.196 us; speedup vs baseline: 1.7645x; 1.7645x over previous
//
#include <hip/hip_runtime.h>
#include <hip/hip_bf16.h>

typedef unsigned short u16;
typedef unsigned int u32;
typedef __attribute__((ext_vector_type(8))) short bf16x8;
typedef __attribute__((ext_vector_type(4))) float f32x4;
typedef __attribute__((ext_vector_type(8))) u16 u16x8;
typedef __attribute__((ext_vector_type(4))) u16 u16x4;

#define NN 20000
#define NE 320000
#define HC 512     // heads*channels = 4*128

__device__ __forceinline__ float bf2f(u16 u){ return __uint_as_float(((u32)u)<<16); }
__device__ __forceinline__ u16 f2bf(float x){
  __hip_bfloat16 h = __float2bfloat16(x);
  return *reinterpret_cast<u16*>(&h);
}
__device__ __forceinline__ float escore(float x){
  float e = x > 0.f ? x : 0.2f*x;
  return __expf(fminf(e, 80.f));
}

// ---------------- cast x f32 -> bf16 ----------------
__global__ __launch_bounds__(256) void cast_kernel(const float* __restrict__ in, u16* __restrict__ out, int total){
  int i = (blockIdx.x*256 + threadIdx.x)*4;
  if (i >= total) return;
  float4 v = *(const float4*)(in + i);
  u16x4 o = { f2bf(v.x), f2bf(v.y), f2bf(v.z), f2bf(v.w) };
  *(u16x4*)(out + i) = o;
}

// ---------------- transpose+cast W f32 [K,N] -> WT bf16 [N,K] ----------------
__global__ __launch_bounds__(256) void transpose_cast(const float* __restrict__ W, u16* __restrict__ WT,
                                                      int K, int N){
  __shared__ u16 t[32][33];
  int bx = blockIdx.x*32;   // along N
  int by = blockIdx.y*32;   // along K
  int tx = threadIdx.x & 31, ty = threadIdx.x >> 5;  // 32x8
  for (int r = ty; r < 32; r += 8) t[r][tx] = f2bf(W[(size_t)(by+r)*N + bx + tx]);
  __syncthreads();
  for (int r = ty; r < 32; r += 8) WT[(size_t)(bx+r)*K + by + tx] = t[tx][r];
}

// ---------------- edge dtype detect + normalize ----------------
__global__ void detect_kernel(const int* __restrict__ ei, int* __restrict__ flag){
  __shared__ int nz;
  if (threadIdx.x == 0) nz = 0;
  __syncthreads();
  int c = 0;
  for (int k = threadIdx.x; k < 4096; k += 256) if (ei[2*k + 1] != 0) c++;
  atomicAdd(&nz, c);
  __syncthreads();
  if (threadIdx.x == 0) *flag = (nz == 0) ? 1 : 0;   // 1 => data is int64
}

__global__ __launch_bounds__(256) void normalize_edges(const int* __restrict__ ei, const int* __restrict__ flag,
    int* __restrict__ src, int* __restrict__ dst, int E){
  int e = blockIdx.x*256 + threadIdx.x;
  if (e >= E) return;
  if (*flag){ src[e] = ei[2*e]; dst[e] = ei[2*(E + e)]; }
  else      { src[e] = ei[e];   dst[e] = ei[E + e]; }
}

// ---------------- GEMM: C[M,512](bf16) = A[M,K](bf16) * BT[512,K](bf16)^T ----------------
__global__ __launch_bounds__(256) void gemm_bf16(const u16* __restrict__ A, const u16* __restrict__ BT,
                                                 u16* __restrict__ C, int M, int K){
  __shared__ __align__(16) u16 Ads[128][64];
  __shared__ __align__(16) u16 Bds[128][64];
  const int bm = blockIdx.x, bn = blockIdx.y;
  const int tid = threadIdx.x;
  const int lane = tid & 63, wid = tid >> 6;
  const int wr = (wid >> 1) << 6, wc = (wid & 1) << 6;
  f32x4 acc[4][4] = {};
  const int row0 = bm*128;
  for (int k0 = 0; k0 < K; k0 += 64){
    #pragma unroll
    for (int p = 0; p < 4; ++p){
      int idx = p*256 + tid;
      int r = idx >> 3;
      int c = (idx & 7) << 3;
      int cs = c ^ ((r & 7) << 3);   // XOR swizzle (16B granules)
      u16x8 va = {};
      int gr = row0 + r;
      if (gr < M) va = *(const u16x8*)(A + (size_t)gr*K + k0 + c);
      *(u16x8*)&Ads[r][cs] = va;
      u16x8 vb = *(const u16x8*)(BT + (size_t)(bn*128 + r)*K + k0 + c);
      *(u16x8*)&Bds[r][cs] = vb;
    }
    __syncthreads();
    #pragma unroll
    for (int kk = 0; kk < 64; kk += 32){
      const int lr = lane & 15;
      const int lk = kk + ((lane >> 4) << 3);
      bf16x8 a[4], b[4];
      #pragma unroll
      for (int i = 0; i < 4; ++i){
        int ar = wr + 16*i + lr;
        a[i] = *(const bf16x8*)&Ads[ar][lk ^ ((ar & 7) << 3)];
      }
      #pragma unroll
      for (int j = 0; j < 4; ++j){
        int br = wc + 16*j + lr;
        b[j] = *(const bf16x8*)&Bds[br][lk ^ ((br & 7) << 3)];
      }
      #pragma unroll
      for (int i = 0; i < 4; ++i)
        #pragma unroll
        for (int j = 0; j < 4; ++j)
          acc[i][j] = __builtin_amdgcn_mfma_f32_16x16x32_bf16(a[i], b[j], acc[i][j], 0, 0, 0);
    }
    __syncthreads();
  }
  const int lr = lane & 15, r4 = (lane >> 4) << 2;
  #pragma unroll
  for (int i = 0; i < 4; ++i)
    #pragma unroll
    for (int j = 0; j < 4; ++j){
      int col = bn*128 + wc + 16*j + lr;
      #pragma unroll
      for (int r = 0; r < 4; ++r){
        int row = row0 + wr + 16*i + r4 + r;
        if (row < M) C[(size_t)row*HC + col] = f2bf(acc[i][j][r]);
      }
    }
}

// ---------------- per-node attention coefficients a_s, a_d ----------------
__global__ __launch_bounds__(256) void asad_kernel(const u16* __restrict__ h,
    const float* __restrict__ attS, const float* __restrict__ attD,
    float* __restrict__ a_s, float* __restrict__ a_d, int N){
  int wid = blockIdx.x*4 + (threadIdx.x >> 6);
  if (wid >= N) return;
  int lane = threadIdx.x & 63;
  u16x8 v = *(const u16x8*)(h + (size_t)wid*HC + lane*8);
  float4 s0 = *(const float4*)(attS + lane*8);
  float4 s1 = *(const float4*)(attS + lane*8 + 4);
  float4 d0 = *(const float4*)(attD + lane*8);
  float4 d1 = *(const float4*)(attD + lane*8 + 4);
  float sv[8] = {s0.x,s0.y,s0.z,s0.w,s1.x,s1.y,s1.z,s1.w};
  float dv[8] = {d0.x,d0.y,d0.z,d0.w,d1.x,d1.y,d1.z,d1.w};
  float ps = 0.f, pd = 0.f;
  #pragma unroll
  for (int t = 0; t < 8; ++t){ float hv = bf2f(v[t]); ps += hv*sv[t]; pd += hv*dv[t]; }
  #pragma unroll
  for (int off = 1; off < 16; off <<= 1){
    ps += __shfl_xor(ps, off, 64);
    pd += __shfl_xor(pd, off, 64);
  }
  if ((lane & 15) == 0){
    int hh = lane >> 4;
    a_s[wid*4 + hh] = ps;
    a_d[wid*4 + hh] = pd;
  }
}

// ---------------- edge sort by dst: histogram / scan / scatter ----------------
__global__ __launch_bounds__(256) void hist_kernel(const int* __restrict__ dst, int* __restrict__ cnt, int E){
  int e = blockIdx.x*256 + threadIdx.x;
  if (e < E) atomicAdd(&cnt[dst[e]], 1);
}

// thread-sequential chunks + one block-wide scan (single barrier phase)
__global__ __launch_bounds__(1024) void scan_kernel(const int* __restrict__ cnt,
    int* __restrict__ offs, int* __restrict__ cur, int N){
  __shared__ int bsum[1024];
  int tid = threadIdx.x;
  const int CH = (N + 1023) >> 10;
  int lo = tid*CH, hi = min(lo + CH, N);
  int s = 0;
  for (int i = lo; i < hi; ++i) s += cnt[i];
  bsum[tid] = s;
  __syncthreads();
  for (int off = 1; off < 1024; off <<= 1){
    int t = (tid >= off) ? bsum[tid - off] : 0;
    __syncthreads();
    bsum[tid] += t;
    __syncthreads();
  }
  int run = (tid > 0) ? bsum[tid - 1] : 0;
  for (int i = lo; i < hi; ++i){
    offs[i] = run; cur[i] = run; run += cnt[i];
  }
  if (tid == 1023) offs[N] = bsum[1023];
}

__global__ __launch_bounds__(256) void scatter_kernel(const int* __restrict__ src, const int* __restrict__ dst,
    int* __restrict__ cur, int* __restrict__ src_sorted, int E){
  int e = blockIdx.x*256 + threadIdx.x;
  if (e >= E) return;
  int d = dst[e];
  int pos = atomicAdd(&cur[d], 1);
  src_sorted[pos] = src[e];
}

// ---------------- fused aggregation: scores inline, one wave per dst ----------------
// MODE 0/1: epilogue = +bias, leaky(0.01) -> bf16 act.  MODE 2: head-mean + b3 -> f32 hfin.
template<int MODE>
__global__ __launch_bounds__(256) void agg_kernel(const u16* __restrict__ h,
    const int* __restrict__ srcs, const int* __restrict__ offs,
    const float* __restrict__ a_s, const float* __restrict__ a_d,
    const float* __restrict__ bias, void* __restrict__ outp, int N){
  int d = blockIdx.x*4 + (threadIdx.x >> 6);
  if (d >= N) return;
  int lane = threadIdx.x & 63;
  int head = lane >> 4;
  float adv = a_d[d*4 + head];
  float acc[8];
  float dsum;
  {
    // self loop
    float w = escore(a_s[d*4 + head] + adv);
    dsum = w;
    u16x8 v = *(const u16x8*)(h + (size_t)d*HC + lane*8);
    #pragma unroll
    for (int t = 0; t < 8; ++t) acc[t] = w*bf2f(v[t]);
  }
  int p0 = offs[d], p1 = offs[d+1];
  int p = p0;
  for (; p + 3 < p1; p += 4){
    int s0 = srcs[p], s1 = srcs[p+1], s2 = srcs[p+2], s3 = srcs[p+3];
    float w0 = escore(a_s[s0*4 + head] + adv);
    float w1 = escore(a_s[s1*4 + head] + adv);
    float w2 = escore(a_s[s2*4 + head] + adv);
    float w3 = escore(a_s[s3*4 + head] + adv);
    u16x8 v0 = *(const u16x8*)(h + (size_t)s0*HC + lane*8);
    u16x8 v1 = *(const u16x8*)(h + (size_t)s1*HC + lane*8);
    u16x8 v2 = *(const u16x8*)(h + (size_t)s2*HC + lane*8);
    u16x8 v3 = *(const u16x8*)(h + (size_t)s3*HC + lane*8);
    dsum += w0 + w1 + w2 + w3;
    #pragma unroll
    for (int t = 0; t < 8; ++t)
      acc[t] += w0*bf2f(v0[t]) + w1*bf2f(v1[t]) + w2*bf2f(v2[t]) + w3*bf2f(v3[t]);
  }
  for (; p < p1; ++p){
    int s = srcs[p];
    float w = escore(a_s[s*4 + head] + adv);
    u16x8 v = *(const u16x8*)(h + (size_t)s*HC + lane*8);
    dsum += w;
    #pragma unroll
    for (int t = 0; t < 8; ++t) acc[t] += w*bf2f(v[t]);
  }
  float inv = 1.0f / (dsum + 1e-16f);
  if (MODE < 2){
    u16* act = (u16*)outp;
    u16x8 o;
    #pragma unroll
    for (int t = 0; t < 8; ++t){
      float x = acc[t]*inv + bias[lane*8 + t];
      x = x > 0.f ? x : 0.01f*x;
      o[t] = f2bf(x);
    }
    *(u16x8*)(act + (size_t)d*HC + lane*8) = o;
  } else {
    #pragma unroll
    for (int t = 0; t < 8; ++t){
      acc[t] *= inv;
      acc[t] += __shfl_xor(acc[t], 16, 64);
      acc[t] += __shfl_xor(acc[t], 32, 64);
    }
    if (lane < 16){
      float* hf = (float*)outp;
      int c0 = lane*8;
      float4 o0 = {0.25f*acc[0] + bias[c0+0], 0.25f*acc[1] + bias[c0+1],
                   0.25f*acc[2] + bias[c0+2], 0.25f*acc[3] + bias[c0+3]};
      float4 o1 = {0.25f*acc[4] + bias[c0+4], 0.25f*acc[5] + bias[c0+5],
                   0.25f*acc[6] + bias[c0+6], 0.25f*acc[7] + bias[c0+7]};
      *(float4*)(hf + (size_t)d*128 + c0)     = o0;
      *(float4*)(hf + (size_t)d*128 + c0 + 4) = o1;
    }
  }
}

// ---------------- final FC + split + exp -> f32 out ----------------
__global__ __launch_bounds__(128) void fc_kernel(const float* __restrict__ hfin, const float* __restrict__ W,
    const float* __restrict__ b, float* __restrict__ outp, int N){
  __shared__ float hl[128];
  int n = blockIdx.x, o = threadIdx.x;
  hl[o] = hfin[(size_t)n*128 + o];
  __syncthreads();
  float acc = b[o];
  #pragma unroll 8
  for (int k = 0; k < 128; ++k) acc += hl[k]*W[k*128 + o];
  if (o < 64) outp[(size_t)n*64 + o] = acc;
  else        outp[(size_t)N*64 + (size_t)n*64 + (o - 64)] = expf(acc);
}

extern "C" void kernel_launch(void* const* d_in, const int* in_sizes, int n_in,
                              void* d_out, int out_size, void* d_ws, size_t ws_size,
                              hipStream_t stream){
  const float* x    = (const float*)d_in[0];
  const int* ei     = (const int*)d_in[1];
  const float* W1   = (const float*)d_in[2];
  const float* att1s= (const float*)d_in[3];
  const float* att1d= (const float*)d_in[4];
  const float* b1   = (const float*)d_in[5];
  const float* W2   = (const float*)d_in[6];
  const float* att2s= (const float*)d_in[7];
  const float* att2d= (const float*)d_in[8];
  const float* b2   = (const float*)d_in[9];
  const float* W3   = (const float*)d_in[10];
  const float* att3s= (const float*)d_in[11];
  const float* att3d= (const float*)d_in[12];
  const float* b3   = (const float*)d_in[13];
  const float* fcW  = (const float*)d_in[14];
  const float* fcb  = (const float*)d_in[15];
  float* outp = (float*)d_out;

  char* ws = (char*)d_ws;
  size_t off = 0;
  auto alloc = [&](size_t bytes) -> void* {
    void* p = ws + off;
    off = (off + bytes + 255) & ~(size_t)255;
    return p;
  };
  u16*   xb     = (u16*)  alloc((size_t)NN*256*2);     // 10.2 MB
  u16*   h      = (u16*)  alloc((size_t)NN*HC*2);      // 20.5 MB
  u16*   act    = (u16*)  alloc((size_t)NN*HC*2);      // 20.5 MB
  float* hfin   = (float*)alloc((size_t)NN*128*4);     // 10.2 MB
  float* a_s    = (float*)alloc((size_t)NN*4*4);
  float* a_d    = (float*)alloc((size_t)NN*4*4);
  int*   cnt    = (int*)  alloc((size_t)NN*4);
  int*   cur    = (int*)  alloc((size_t)NN*4);
  int*   offs   = (int*)  alloc((size_t)(NN+1)*4);
  int*   src32  = (int*)  alloc((size_t)NE*4);
  int*   dst32  = (int*)  alloc((size_t)NE*4);
  int*   srcs   = (int*)  alloc((size_t)NE*4);
  u16*   WT1    = (u16*)  alloc((size_t)512*256*2);
  u16*   WT2    = (u16*)  alloc((size_t)512*512*2);
  u16*   WT3    = (u16*)  alloc((size_t)512*512*2);
  int*   flag   = (int*)  alloc(256);

  // ---- input prep ----
  cast_kernel<<<5000, 256, 0, stream>>>(x, xb, NN*256);
  transpose_cast<<<dim3(16, 8),  256, 0, stream>>>(W1, WT1, 256, 512);
  transpose_cast<<<dim3(16, 16), 256, 0, stream>>>(W2, WT2, 512, 512);
  transpose_cast<<<dim3(16, 16), 256, 0, stream>>>(W3, WT3, 512, 512);

  detect_kernel<<<1, 256, 0, stream>>>(ei, flag);
  normalize_edges<<<1250, 256, 0, stream>>>(ei, flag, src32, dst32, NE);

  // ---- edge sort by dst (shared across all 3 layers) ----
  hipMemsetAsync(cnt, 0, (size_t)NN*4, stream);
  hist_kernel<<<1250, 256, 0, stream>>>(dst32, cnt, NE);
  scan_kernel<<<1, 1024, 0, stream>>>(cnt, offs, cur, NN);
  scatter_kernel<<<1250, 256, 0, stream>>>(src32, dst32, cur, srcs, NE);

  const float* attS[3] = {att1s, att2s, att3s};
  const float* attD[3] = {att1d, att2d, att3d};
  const u16*   WT[3]   = {WT1, WT2, WT3};
  const int    Kd[3]   = {256, 512, 512};

  for (int layer = 0; layer < 3; ++layer){
    const u16* Ain = (layer == 0) ? xb : act;
    gemm_bf16<<<dim3(157, 4), 256, 0, stream>>>(Ain, WT[layer], h, NN, Kd[layer]);
    asad_kernel<<<5000, 256, 0, stream>>>(h, attS[layer], attD[layer], a_s, a_d, NN);
    if (layer == 0)
      agg_kernel<0><<<5000, 256, 0, stream>>>(h, srcs, offs, a_s, a_d, b1, act, NN);
    else if (layer == 1)
      agg_kernel<1><<<5000, 256, 0, stream>>>(h, srcs, offs, a_s, a_d, b2, act, NN);
    else
      agg_kernel<2><<<5000, 256, 0, stream>>>(h, srcs, offs, a_s, a_d, b3, hfin, NN);
  }

  fc_kernel<<<NN, 128, 0, stream>>>(hfin, fcW, fcb, outp, NN);
}